// Round 16
// baseline (3988.444 us; speedup 1.0000x reference)
//
#include <hip/hip_runtime.h>
#include <stdint.h>
#include <stddef.h>

#define T_LEN 1024
#define BATCH 64
#define KDIM  256
#define HID   256
#define NGATE 5
#define GROWS (NGATE * HID)   // 1280
#define NGT   (GROWS / 16)    // 80 gate tiles of 16 rows
#define NSWG  4               // scan WGs: 16 batch rows each, fully independent

#define L2E  1.442695041f
#define L2E2 2.885390082f

typedef __attribute__((ext_vector_type(8))) short s16x8;   // 8 bf16
typedef __attribute__((ext_vector_type(4))) float f32x4;
typedef __attribute__((ext_vector_type(4))) int   i32x4;
typedef __attribute__((ext_vector_type(2))) unsigned int u32x2;

static __device__ __forceinline__ uint16_t f2bf(float f) {
  uint32_t u = __float_as_uint(f);
  return (uint16_t)((u + 0x7fffu + ((u >> 16) & 1u)) >> 16);   // RNE
}
static __device__ __forceinline__ float bf2f(uint16_t b) {
  return __uint_as_float(((uint32_t)b) << 16);
}
static __device__ __forceinline__ s16x8 cvt8(const float* __restrict__ p) {
  float4 a = *reinterpret_cast<const float4*>(p);
  float4 b = *reinterpret_cast<const float4*>(p + 4);
  union { s16x8 v; uint16_t u[8]; } r;
  r.u[0] = f2bf(a.x); r.u[1] = f2bf(a.y); r.u[2] = f2bf(a.z); r.u[3] = f2bf(a.w);
  r.u[4] = f2bf(b.x); r.u[5] = f2bf(b.y); r.u[6] = f2bf(b.z); r.u[7] = f2bf(b.w);
  return r.v;
}
static __device__ __forceinline__ float rcp_hw(float x) {
  float r; asm("v_rcp_f32 %0, %1" : "=v"(r) : "v"(x)); return r;
}
static __device__ __forceinline__ float exp2_hw(float x) {
  float r; asm("v_exp_f32 %0, %1" : "=v"(r) : "v"(x)); return r;
}
static __device__ __forceinline__ float exp2_neg(float x) {
  float r; asm("v_exp_f32 %0, -%1" : "=v"(r) : "v"(x)); return r;
}
// inputs PRE-SCALED: sigm2 expects x*log2e, tanh2 expects x*2*log2e
static __device__ __forceinline__ float sigm2(float xs) {
  return rcp_hw(1.f + exp2_neg(xs));
}
static __device__ __forceinline__ float tanh2(float xs) {
  return __builtin_fmaf(-2.f, rcp_hw(1.f + exp2_hw(xs)), 1.f);
}
// LDS swizzle for hq: XOR 16B-block index with row (breaks stride-256B bank collision)
static __device__ __forceinline__ int swz(int row, int col) {
  return ((((col >> 4) ^ (row & 15)) << 4) | (col & 15));
}

// MFMA via inline asm. R13-proven classes: acc "+a" (native accumulate), resident
// weights "a", LDS weights "v". NEW (R16): first-ks forms take a shared AGPR zero
// as srcC with early-clobber "=&a" dst — removes 20 per-step accvgpr_write inits.
// Total AGPR: 48 W + 20 acc + 4 zero = 72 (far below the ~100-120 cliff that broke
// R14/R15).
#define MFMA_AW(acc, A, W) \
  asm("v_mfma_i32_16x16x64_i8 %0, %1, %2, %0" : "+a"(acc) : "v"(A), "a"(W))
#define MFMA_AV(acc, A, B) \
  asm("v_mfma_i32_16x16x64_i8 %0, %1, %2, %0" : "+a"(acc) : "v"(A), "v"(B))
#define MFMA_ZW(acc, A, W, Z) \
  asm("v_mfma_i32_16x16x64_i8 %0, %1, %2, %3" : "=&a"(acc) : "v"(A), "a"(W), "a"(Z))
#define MFMA_ZV(acc, A, B, Z) \
  asm("v_mfma_i32_16x16x64_i8 %0, %1, %2, %3" : "=&a"(acc) : "v"(A), "v"(B), "a"(Z))

// ---------------- setup: W_ih -> bf16 pre-scaled by exp2-domain factor, c0 -> cbuf ----------------
__global__ void setup_kernel(const float* __restrict__ Wih, const float* __restrict__ c0,
                             uint16_t* __restrict__ wihb, float* __restrict__ cbuf) {
  int i = blockIdx.x * 256 + threadIdx.x;
  if (i < GROWS * KDIM) {
    int gate = (i >> 8) >> 8;               // row = i/256; gate = row/256
    float kg = (gate == 2) ? L2E2 : L2E;
    wihb[i] = f2bf(Wih[i] * kg);
  }
  if (i < BATCH * HID) cbuf[i] = c0[i];
}

// ---------------- W_hh -> int8 per-row quant (raw scale; exp2 factor folded in scan) ----------------
__global__ void wquant_kernel(const float* __restrict__ Whh,
                              int8_t* __restrict__ wq, float* __restrict__ wsc) {
  int row = blockIdx.x * 256 + threadIdx.x;
  if (row >= GROWS) return;
  const float* wr = Whh + (size_t)row * KDIM;
  float mx = 1e-30f;
  for (int k = 0; k < KDIM; ++k) mx = fmaxf(mx, fabsf(wr[k]));
  wsc[row] = mx / 127.f;
  const float inv = 127.f / mx;
  int8_t* q = wq + (size_t)row * KDIM;
  for (int k = 0; k < KDIM; ++k) q[k] = (int8_t)__float2int_rn(wr[k] * inv);
}

// ---------------- x projection (bf16 MFMA; bias pre-scaled like W_ih) — R13 verbatim ----------------
__global__ __launch_bounds__(256, 2)
void xproj_kernel(const float* __restrict__ x, const uint16_t* __restrict__ wihb,
                  const float* __restrict__ bias, uint16_t* __restrict__ xp, int t0) {
  const int w = threadIdx.x >> 6, lane = threadIdx.x & 63;
  const int r16 = lane & 15, ke = (lane >> 4) * 8;
  const int tA = t0 + (int)blockIdx.x * 2;

  s16x8 A[2][8];
#pragma unroll
  for (int tt = 0; tt < 2; ++tt) {
    const float* ap = x + ((size_t)(tA + tt) * BATCH + w * 16 + r16) * KDIM + ke;
#pragma unroll
    for (int ks = 0; ks < 8; ++ks) A[tt][ks] = cvt8(ap + ks * 32);
  }
  for (int gt = 0; gt < NGT; ++gt) {
    const uint16_t* bp = wihb + (size_t)(gt * 16 + r16) * KDIM + ke;
    s16x8 B[8];
#pragma unroll
    for (int ks = 0; ks < 8; ++ks) B[ks] = *reinterpret_cast<const s16x8*>(bp + ks * 32);
    const float kg = ((gt >> 4) == 2) ? L2E2 : L2E;
    const float bv = bias[gt * 16 + r16] * kg;
#pragma unroll
    for (int tt = 0; tt < 2; ++tt) {
      f32x4 acc = {};
#pragma unroll
      for (int ks = 0; ks < 8; ++ks)
        acc = __builtin_amdgcn_mfma_f32_16x16x32_bf16(A[tt][ks], B[ks], acc, 0, 0, 0);
      const int lt = (int)blockIdx.x * 2 + tt;
      uint32_t w0 = (uint32_t)f2bf(acc[0] + bv) | ((uint32_t)f2bf(acc[1] + bv) << 16);
      uint32_t w1 = (uint32_t)f2bf(acc[2] + bv) | ((uint32_t)f2bf(acc[3] + bv) << 16);
      u32x2 pk = {w0, w1};
      u32x2* dst = (u32x2*)((uint32_t*)(xp + ((size_t)(lt * 4 + w) * NGT + gt) * 256) + lane * 2);
      __builtin_nontemporal_store(pk, dst);
    }
  }
}

// ---------------- sequential scan: 4 independent WGs, 16 waves each ----------------
// R13 structure (proven 3.34 us/step): gates {i,f,g} weights AGPR-resident; gates
// {o,r} in LDS fragments; acc in AGPRs; 136 KB LDS (1 WG/CU); h via LDS i8 double
// buffer + one raw s_barrier/step; xp/m prefetched one step ahead; exp2-domain
// gate math. ONLY change (R16): shared AGPR zero as MFMA srcC on the first k-step
// (removes the 20 per-step accvgpr_write zero-inits).
__global__ __launch_bounds__(1024, 4)
void scan_kernel(const float* __restrict__ mIn, const int8_t* __restrict__ wq,
                 const float* __restrict__ wsc, const uint16_t* __restrict__ xp,
                 const float* __restrict__ h_src, float* __restrict__ cbuf,
                 float* __restrict__ seq, float* __restrict__ hT, float* __restrict__ cT,
                 int s0, int s1) {
  struct SW {
    int8_t w[16][2][4][1024];   // [wave][ldsgate][ks][lane*16]  128 KB
    int8_t hq[2][16][256];      // h double buffer, swizzled       8 KB
  };
  __shared__ SW sl;
  const int wg = blockIdx.x;                // batch tile (16 rows)
  const int v = threadIdx.x >> 6;           // wave 0..15 = H col-block
  const int lane = threadIdx.x & 63;
  const int r16 = lane & 15, g4 = lane >> 4;
  const int bj0 = g4 * 4;                   // batch row (within tile) base, C layout
  const int brow = wg * 16;                 // global batch base
  const int col = v * 16 + r16;             // owned H column

  // AGPR-resident gates 0..2 + exp2-scaled dequant scales for all gates
  i32x4 Wf0[4], Wf1[4], Wf2[4];
  float sc[NGATE];
#pragma unroll
  for (int g = 0; g < NGATE; ++g) {
    const float kg = (g == 2) ? L2E2 : L2E;
    sc[g] = wsc[g * 256 + col] * (kg / 127.f);
  }
  {
    const int8_t* wp0 = wq + (size_t)(0 * 256 + col) * KDIM + g4 * 16;
    const int8_t* wp1 = wq + (size_t)(1 * 256 + col) * KDIM + g4 * 16;
    const int8_t* wp2 = wq + (size_t)(2 * 256 + col) * KDIM + g4 * 16;
#pragma unroll
    for (int ks = 0; ks < 4; ++ks) {
      Wf0[ks] = *reinterpret_cast<const i32x4*>(wp0 + ks * 64);
      Wf1[ks] = *reinterpret_cast<const i32x4*>(wp1 + ks * 64);
      Wf2[ks] = *reinterpret_cast<const i32x4*>(wp2 + ks * 64);
    }
  }
  // LDS-resident gates 3,4: each wave writes its own fragments in per-lane order
#pragma unroll
  for (int gl = 0; gl < 2; ++gl) {
    const int grow = (3 + gl) * 256 + col;
    const int8_t* wp = wq + (size_t)grow * KDIM + g4 * 16;
#pragma unroll
    for (int ks = 0; ks < 4; ++ks)
      *reinterpret_cast<i32x4*>(&sl.w[v][gl][ks][lane * 16]) =
          *reinterpret_cast<const i32x4*>(wp + ks * 64);
  }

  float c[4];
#pragma unroll
  for (int j = 0; j < 4; ++j)
    c[j] = cbuf[(size_t)(brow + bj0 + j) * HID + col];

  // entry h (h0 or seq[s0-1]) -> quantized into LDS buf parity s0&1
  {
    const int p0 = s0 & 1;
#pragma unroll
    for (int e = 0; e < 4; ++e) {
      int t = (int)threadIdx.x * 4 + e;
      int row = t >> 8, cc = t & 255;
      float hv = h_src[(size_t)(brow + row) * HID + cc];
      int q = __float2int_rn(fminf(fmaxf(hv * 127.f, -127.f), 127.f));
      sl.hq[p0][row][swz(row, cc)] = (int8_t)q;
    }
  }
  __syncthreads();

  // hoisted swizzled LDS byte offsets (within one 4 KB hq buffer)
  int aoff[4], woff[4];
#pragma unroll
  for (int ks = 0; ks < 4; ++ks) aoff[ks] = r16 * 256 + swz(r16, (g4 + 4 * ks) * 16);
#pragma unroll
  for (int j = 0; j < 4; ++j) woff[j] = (bj0 + j) * 256 + swz(bj0 + j, col);

  // stepping pointers
  const uint16_t* xpb = xp + ((size_t)wg * NGT + v) * 256 + lane * 4;
  const float*    mb  = mIn + ((size_t)s0 * BATCH + brow + bj0) * HID + col;
  float*          sqb = seq + ((size_t)s0 * BATCH + brow + bj0) * HID + col;

  // prologue prefetch for step s0
  u32x2 xpf[NGATE];
  float mv[4];
#pragma unroll
  for (int g = 0; g < NGATE; ++g)
    xpf[g] = *reinterpret_cast<const u32x2*>(xpb + g * 4096);
#pragma unroll
  for (int j = 0; j < 4; ++j) mv[j] = mb[j * HID];

  int8_t* const hq0 = &sl.hq[0][0][0];
  const i32x4 zA = {0, 0, 0, 0};   // loop-invariant AGPR zero (srcC of first-ks MFMAs)

  for (int s = s0; s < s1; ++s) {
    const int p = s & 1;
    const int8_t* hr = hq0 + p * 4096;        // read buffer
    int8_t*       hw = hq0 + (p ^ 1) * 4096;  // write buffer

    // MFMA phase: A from hq; gates 0-2 weights from AGPR, gates 3-4 from LDS.
    // First k-step consumes the shared AGPR zero as srcC (no per-step acc init).
    i32x4 a0, a1, a2, a3, a4;
    __builtin_amdgcn_s_setprio(1);
    {
      i32x4 A = *reinterpret_cast<const i32x4*>(hr + aoff[0]);
      MFMA_ZW(a0, A, Wf0[0], zA);
      MFMA_ZW(a1, A, Wf1[0], zA);
      MFMA_ZW(a2, A, Wf2[0], zA);
      i32x4 b0 = *reinterpret_cast<const i32x4*>(&sl.w[v][0][0][lane * 16]);
      MFMA_ZV(a3, A, b0, zA);
      i32x4 b1 = *reinterpret_cast<const i32x4*>(&sl.w[v][1][0][lane * 16]);
      MFMA_ZV(a4, A, b1, zA);
    }
#pragma unroll
    for (int ks = 1; ks < 4; ++ks) {
      i32x4 A = *reinterpret_cast<const i32x4*>(hr + aoff[ks]);
      MFMA_AW(a0, A, Wf0[ks]);
      MFMA_AW(a1, A, Wf1[ks]);
      MFMA_AW(a2, A, Wf2[ks]);
      i32x4 b0 = *reinterpret_cast<const i32x4*>(&sl.w[v][0][ks][lane * 16]);
      MFMA_AV(a3, A, b0);
      i32x4 b1 = *reinterpret_cast<const i32x4*>(&sl.w[v][1][ks][lane * 16]);
      MFMA_AV(a4, A, b1);
    }
    __builtin_amdgcn_s_setprio(0);

    // gate math (consumes xpf/mv prefetched one step ago); exp2-domain
    float hnew[4];
#pragma unroll
    for (int j = 0; j < 4; ++j) {
#define XPV(g) bf2f((uint16_t)((j & 1) ? (xpf[g][j >> 1] >> 16) : (xpf[g][j >> 1] & 0xffff)))
      const float gi = __builtin_fmaf((float)a0[j], sc[0], XPV(0));
      const float gf = __builtin_fmaf((float)a1[j], sc[1], XPV(1));
      const float gg = __builtin_fmaf((float)a2[j], sc[2], XPV(2));
      const float go = __builtin_fmaf((float)a3[j], sc[3], XPV(3));
      const float gr = __builtin_fmaf((float)a4[j], sc[4], XPV(4));
#undef XPV
      const float cn = sigm2(gf) * c[j] + sigm2(gi) * tanh2(gg) + sigm2(gr) * mv[j];
      c[j] = cn;
      hnew[j] = sigm2(go) * tanh2(cn * L2E2);
    }

    // prefetch next step into the (now free) xpf/mv regs — overlaps barrier + next MFMA
    const uint16_t* xpb_n = xpb + 4 * NGT * 256;                 // beyond-chunk read stays in ws
    const float*    mb_n  = (s + 1 < s1) ? mb + BATCH * HID : mb;
#pragma unroll
    for (int g = 0; g < NGATE; ++g)
      xpf[g] = *reinterpret_cast<const u32x2*>(xpb_n + g * 4096);
#pragma unroll
    for (int j = 0; j < 4; ++j) mv[j] = mb_n[j * HID];
    xpb = xpb_n; mb = mb_n;

    // outputs + quantized h into next LDS buffer
#pragma unroll
    for (int j = 0; j < 4; ++j) {
      __builtin_nontemporal_store(hnew[j], sqb + j * HID);
      hw[woff[j]] = (int8_t)__float2int_rn(hnew[j] * 127.f);
    }
    if (s == T_LEN - 1) {
#pragma unroll
      for (int j = 0; j < 4; ++j) {
        hT[(size_t)(brow + bj0 + j) * HID + col] = hnew[j];
        cT[(size_t)(brow + bj0 + j) * HID + col] = c[j];
      }
    }
    sqb += BATCH * HID;

    // raw barrier: only LDS ordering needed (global loads/stores keep flying)
    __builtin_amdgcn_sched_barrier(0);
    asm volatile("s_waitcnt lgkmcnt(0)" ::: "memory");
    __builtin_amdgcn_s_barrier();
    __builtin_amdgcn_sched_barrier(0);
  }

  // persist c for next chunk
#pragma unroll
  for (int j = 0; j < 4; ++j)
    cbuf[(size_t)(brow + bj0 + j) * HID + col] = c[j];
}

extern "C" void kernel_launch(void* const* d_in, const int* in_sizes, int n_in,
                              void* d_out, int out_size, void* d_ws, size_t ws_size,
                              hipStream_t stream) {
  (void)in_sizes; (void)n_in; (void)out_size;
  const float* x    = (const float*)d_in[0];
  const float* mIn  = (const float*)d_in[1];
  const float* h0   = (const float*)d_in[2];
  const float* c0   = (const float*)d_in[3];
  const float* Wih  = (const float*)d_in[4];
  const float* Whh  = (const float*)d_in[5];
  const float* bias = (const float*)d_in[6];
  float* out = (float*)d_out;
  float* seq = out;
  float* hT  = out + (size_t)T_LEN * BATCH * HID;
  float* cT  = hT + (size_t)BATCH * HID;

  // ws: xp(bf16) + wihb(bf16) + wq(i8) + wsc(f32) + cbuf(f32)
  const size_t fixed = (size_t)GROWS * KDIM * 2 + (size_t)GROWS * KDIM
                     + (size_t)GROWS * 4 + (size_t)BATCH * HID * 4 + 4096;
  int tchunk = T_LEN;
  while (tchunk > 2 && (size_t)tchunk * BATCH * GROWS * 2 + fixed > ws_size) tchunk >>= 1;

  char* p = (char*)d_ws;
  uint16_t* xp   = (uint16_t*)p;  p += (size_t)tchunk * BATCH * GROWS * 2;
  uint16_t* wihb = (uint16_t*)p;  p += (size_t)GROWS * KDIM * 2;
  int8_t*   wq   = (int8_t*)p;    p += (size_t)GROWS * KDIM;
  float*    wsc  = (float*)p;     p += (size_t)GROWS * 4;
  float*    cbuf = (float*)p;

  setup_kernel<<<dim3((GROWS * KDIM + 255) / 256), dim3(256), 0, stream>>>(
      Wih, c0, wihb, cbuf);
  wquant_kernel<<<dim3((GROWS + 255) / 256), dim3(256), 0, stream>>>(Whh, wq, wsc);
  for (int s0 = 0; s0 < T_LEN; s0 += tchunk) {
    xproj_kernel<<<dim3(tchunk / 2), dim3(256), 0, stream>>>(x, wihb, bias, xp, s0);
    const float* h_src = (s0 == 0) ? h0 : (seq + (size_t)(s0 - 1) * BATCH * HID);
    scan_kernel<<<dim3(NSWG), dim3(1024), 0, stream>>>(
        mIn, wq, wsc, xp, h_src, cbuf, seq, hT, cT, s0, s0 + tchunk);
  }
}

// Round 17
// 3550.483 us; speedup vs baseline: 1.1234x; 1.1234x over previous
//
#include <hip/hip_runtime.h>
#include <stdint.h>
#include <stddef.h>

#define T_LEN 1024
#define BATCH 64
#define KDIM  256
#define HID   256
#define NGATE 5
#define GROWS (NGATE * HID)   // 1280
#define NGT   (GROWS / 16)    // 80 gate tiles of 16 rows
#define NSWG  4               // scan WGs: 16 batch rows each, fully independent

#define L2E  1.442695041f
#define L2E2 2.885390082f

typedef __attribute__((ext_vector_type(8))) short s16x8;   // 8 bf16
typedef __attribute__((ext_vector_type(4))) float f32x4;
typedef __attribute__((ext_vector_type(4))) int   i32x4;
typedef __attribute__((ext_vector_type(2))) unsigned int u32x2;

static __device__ __forceinline__ uint16_t f2bf(float f) {
  uint32_t u = __float_as_uint(f);
  return (uint16_t)((u + 0x7fffu + ((u >> 16) & 1u)) >> 16);   // RNE
}
static __device__ __forceinline__ float bf2f(uint16_t b) {
  return __uint_as_float(((uint32_t)b) << 16);
}
static __device__ __forceinline__ s16x8 cvt8(const float* __restrict__ p) {
  float4 a = *reinterpret_cast<const float4*>(p);
  float4 b = *reinterpret_cast<const float4*>(p + 4);
  union { s16x8 v; uint16_t u[8]; } r;
  r.u[0] = f2bf(a.x); r.u[1] = f2bf(a.y); r.u[2] = f2bf(a.z); r.u[3] = f2bf(a.w);
  r.u[4] = f2bf(b.x); r.u[5] = f2bf(b.y); r.u[6] = f2bf(b.z); r.u[7] = f2bf(b.w);
  return r.v;
}
static __device__ __forceinline__ float rcp_hw(float x) {
  float r; asm("v_rcp_f32 %0, %1" : "=v"(r) : "v"(x)); return r;
}
static __device__ __forceinline__ float exp2_hw(float x) {
  float r; asm("v_exp_f32 %0, %1" : "=v"(r) : "v"(x)); return r;
}
static __device__ __forceinline__ float exp2_neg(float x) {
  float r; asm("v_exp_f32 %0, -%1" : "=v"(r) : "v"(x)); return r;
}
// inputs PRE-SCALED: sigm2 expects x*log2e, tanh2 expects x*2*log2e
static __device__ __forceinline__ float sigm2(float xs) {
  return rcp_hw(1.f + exp2_neg(xs));
}
static __device__ __forceinline__ float tanh2(float xs) {
  return __builtin_fmaf(-2.f, rcp_hw(1.f + exp2_hw(xs)), 1.f);
}
// LDS swizzle for hq: XOR 16B-block index with row (breaks stride-256B bank collision)
static __device__ __forceinline__ int swz(int row, int col) {
  return ((((col >> 4) ^ (row & 15)) << 4) | (col & 15));
}

// MFMA via inline asm: acc pinned in AGPRs ("+a", the native accumulate path);
// resident-gate weights in AGPRs ("a"), LDS-gate weights in VGPRs ("v").
// NOTE (R10/R14/R15/R16 lessons): only the "+a" accumulate form is safe+fast on
// this toolchain; "=&v"/"=&a" zero-src forms regress; >~100 asm-constrained AGPR
// tuples miscompile (weight clobber). 48 W + 20 acc = 68 AGPRs here: proven good.
#define MFMA_AW(acc, A, W) \
  asm("v_mfma_i32_16x16x64_i8 %0, %1, %2, %0" : "+a"(acc) : "v"(A), "a"(W))
#define MFMA_AV(acc, A, B) \
  asm("v_mfma_i32_16x16x64_i8 %0, %1, %2, %0" : "+a"(acc) : "v"(A), "v"(B))

// ---------------- setup: W_ih -> bf16 pre-scaled by exp2-domain factor, c0 -> cbuf ----------------
__global__ void setup_kernel(const float* __restrict__ Wih, const float* __restrict__ c0,
                             uint16_t* __restrict__ wihb, float* __restrict__ cbuf) {
  int i = blockIdx.x * 256 + threadIdx.x;
  if (i < GROWS * KDIM) {
    int gate = (i >> 8) >> 8;               // row = i/256; gate = row/256
    float kg = (gate == 2) ? L2E2 : L2E;
    wihb[i] = f2bf(Wih[i] * kg);
  }
  if (i < BATCH * HID) cbuf[i] = c0[i];
}

// ---------------- W_hh -> int8 per-row quant (raw scale; exp2 factor folded in scan) ----------------
__global__ void wquant_kernel(const float* __restrict__ Whh,
                              int8_t* __restrict__ wq, float* __restrict__ wsc) {
  int row = blockIdx.x * 256 + threadIdx.x;
  if (row >= GROWS) return;
  const float* wr = Whh + (size_t)row * KDIM;
  float mx = 1e-30f;
  for (int k = 0; k < KDIM; ++k) mx = fmaxf(mx, fabsf(wr[k]));
  wsc[row] = mx / 127.f;
  const float inv = 127.f / mx;
  int8_t* q = wq + (size_t)row * KDIM;
  for (int k = 0; k < KDIM; ++k) q[k] = (int8_t)__float2int_rn(wr[k] * inv);
}

// ---------------- x projection (bf16 MFMA; bias pre-scaled like W_ih) ----------------
__global__ __launch_bounds__(256, 2)
void xproj_kernel(const float* __restrict__ x, const uint16_t* __restrict__ wihb,
                  const float* __restrict__ bias, uint16_t* __restrict__ xp, int t0) {
  const int w = threadIdx.x >> 6, lane = threadIdx.x & 63;
  const int r16 = lane & 15, ke = (lane >> 4) * 8;
  const int tA = t0 + (int)blockIdx.x * 2;

  s16x8 A[2][8];
#pragma unroll
  for (int tt = 0; tt < 2; ++tt) {
    const float* ap = x + ((size_t)(tA + tt) * BATCH + w * 16 + r16) * KDIM + ke;
#pragma unroll
    for (int ks = 0; ks < 8; ++ks) A[tt][ks] = cvt8(ap + ks * 32);
  }
  for (int gt = 0; gt < NGT; ++gt) {
    const uint16_t* bp = wihb + (size_t)(gt * 16 + r16) * KDIM + ke;
    s16x8 B[8];
#pragma unroll
    for (int ks = 0; ks < 8; ++ks) B[ks] = *reinterpret_cast<const s16x8*>(bp + ks * 32);
    const float kg = ((gt >> 4) == 2) ? L2E2 : L2E;
    const float bv = bias[gt * 16 + r16] * kg;
#pragma unroll
    for (int tt = 0; tt < 2; ++tt) {
      f32x4 acc = {};
#pragma unroll
      for (int ks = 0; ks < 8; ++ks)
        acc = __builtin_amdgcn_mfma_f32_16x16x32_bf16(A[tt][ks], B[ks], acc, 0, 0, 0);
      const int lt = (int)blockIdx.x * 2 + tt;
      uint32_t w0 = (uint32_t)f2bf(acc[0] + bv) | ((uint32_t)f2bf(acc[1] + bv) << 16);
      uint32_t w1 = (uint32_t)f2bf(acc[2] + bv) | ((uint32_t)f2bf(acc[3] + bv) << 16);
      u32x2 pk = {w0, w1};
      u32x2* dst = (u32x2*)((uint32_t*)(xp + ((size_t)(lt * 4 + w) * NGT + gt) * 256) + lane * 2);
      __builtin_nontemporal_store(pk, dst);
    }
  }
}

// ---------------- sequential scan: 4 independent WGs, 16 waves each ----------------
// Best measured configuration (R13, 3.43 us/step): gates {i,f,g} weights AGPR-
// resident via asm "a"; gates {o,r} in LDS fragments; acc in AGPRs ("+a"); 136 KB
// LDS (guarantees 1 WG/CU); h via LDS i8 double buffer + one raw s_barrier per
// step; xp/m prefetched one step ahead; exp2-domain gate math with v_rcp/v_exp.
__global__ __launch_bounds__(1024, 4)
void scan_kernel(const float* __restrict__ mIn, const int8_t* __restrict__ wq,
                 const float* __restrict__ wsc, const uint16_t* __restrict__ xp,
                 const float* __restrict__ h_src, float* __restrict__ cbuf,
                 float* __restrict__ seq, float* __restrict__ hT, float* __restrict__ cT,
                 int s0, int s1) {
  struct SW {
    int8_t w[16][2][4][1024];   // [wave][ldsgate][ks][lane*16]  128 KB
    int8_t hq[2][16][256];      // h double buffer, swizzled       8 KB
  };
  __shared__ SW sl;
  const int wg = blockIdx.x;                // batch tile (16 rows)
  const int v = threadIdx.x >> 6;           // wave 0..15 = H col-block
  const int lane = threadIdx.x & 63;
  const int r16 = lane & 15, g4 = lane >> 4;
  const int bj0 = g4 * 4;                   // batch row (within tile) base, C layout
  const int brow = wg * 16;                 // global batch base
  const int col = v * 16 + r16;             // owned H column

  // AGPR-resident gates 0..2 + exp2-scaled dequant scales for all gates
  i32x4 Wf0[4], Wf1[4], Wf2[4];
  float sc[NGATE];
#pragma unroll
  for (int g = 0; g < NGATE; ++g) {
    const float kg = (g == 2) ? L2E2 : L2E;
    sc[g] = wsc[g * 256 + col] * (kg / 127.f);
  }
  {
    const int8_t* wp0 = wq + (size_t)(0 * 256 + col) * KDIM + g4 * 16;
    const int8_t* wp1 = wq + (size_t)(1 * 256 + col) * KDIM + g4 * 16;
    const int8_t* wp2 = wq + (size_t)(2 * 256 + col) * KDIM + g4 * 16;
#pragma unroll
    for (int ks = 0; ks < 4; ++ks) {
      Wf0[ks] = *reinterpret_cast<const i32x4*>(wp0 + ks * 64);
      Wf1[ks] = *reinterpret_cast<const i32x4*>(wp1 + ks * 64);
      Wf2[ks] = *reinterpret_cast<const i32x4*>(wp2 + ks * 64);
    }
  }
  // LDS-resident gates 3,4: each wave writes its own fragments in per-lane order
#pragma unroll
  for (int gl = 0; gl < 2; ++gl) {
    const int grow = (3 + gl) * 256 + col;
    const int8_t* wp = wq + (size_t)grow * KDIM + g4 * 16;
#pragma unroll
    for (int ks = 0; ks < 4; ++ks)
      *reinterpret_cast<i32x4*>(&sl.w[v][gl][ks][lane * 16]) =
          *reinterpret_cast<const i32x4*>(wp + ks * 64);
  }

  float c[4];
#pragma unroll
  for (int j = 0; j < 4; ++j)
    c[j] = cbuf[(size_t)(brow + bj0 + j) * HID + col];

  // entry h (h0 or seq[s0-1]) -> quantized into LDS buf parity s0&1
  {
    const int p0 = s0 & 1;
#pragma unroll
    for (int e = 0; e < 4; ++e) {
      int t = (int)threadIdx.x * 4 + e;
      int row = t >> 8, cc = t & 255;
      float hv = h_src[(size_t)(brow + row) * HID + cc];
      int q = __float2int_rn(fminf(fmaxf(hv * 127.f, -127.f), 127.f));
      sl.hq[p0][row][swz(row, cc)] = (int8_t)q;
    }
  }
  __syncthreads();

  // hoisted swizzled LDS byte offsets (within one 4 KB hq buffer)
  int aoff[4], woff[4];
#pragma unroll
  for (int ks = 0; ks < 4; ++ks) aoff[ks] = r16 * 256 + swz(r16, (g4 + 4 * ks) * 16);
#pragma unroll
  for (int j = 0; j < 4; ++j) woff[j] = (bj0 + j) * 256 + swz(bj0 + j, col);

  // stepping pointers
  const uint16_t* xpb = xp + ((size_t)wg * NGT + v) * 256 + lane * 4;
  const float*    mb  = mIn + ((size_t)s0 * BATCH + brow + bj0) * HID + col;
  float*          sqb = seq + ((size_t)s0 * BATCH + brow + bj0) * HID + col;

  // prologue prefetch for step s0
  u32x2 xpf[NGATE];
  float mv[4];
#pragma unroll
  for (int g = 0; g < NGATE; ++g)
    xpf[g] = *reinterpret_cast<const u32x2*>(xpb + g * 4096);
#pragma unroll
  for (int j = 0; j < 4; ++j) mv[j] = mb[j * HID];

  int8_t* const hq0 = &sl.hq[0][0][0];

  for (int s = s0; s < s1; ++s) {
    const int p = s & 1;
    const int8_t* hr = hq0 + p * 4096;        // read buffer
    int8_t*       hw = hq0 + (p ^ 1) * 4096;  // write buffer

    // MFMA phase: A from hq; gates 0-2 weights from AGPR, gates 3-4 from LDS
    i32x4 acc[NGATE];
#pragma unroll
    for (int g = 0; g < NGATE; ++g) acc[g] = i32x4{0, 0, 0, 0};
    __builtin_amdgcn_s_setprio(1);
#pragma unroll
    for (int ks = 0; ks < 4; ++ks) {
      i32x4 A = *reinterpret_cast<const i32x4*>(hr + aoff[ks]);
      MFMA_AW(acc[0], A, Wf0[ks]);
      MFMA_AW(acc[1], A, Wf1[ks]);
      MFMA_AW(acc[2], A, Wf2[ks]);
      i32x4 b0 = *reinterpret_cast<const i32x4*>(&sl.w[v][0][ks][lane * 16]);
      MFMA_AV(acc[3], A, b0);
      i32x4 b1 = *reinterpret_cast<const i32x4*>(&sl.w[v][1][ks][lane * 16]);
      MFMA_AV(acc[4], A, b1);
    }
    __builtin_amdgcn_s_setprio(0);

    // gate math (consumes xpf/mv prefetched one step ago); exp2-domain
    float hnew[4];
#pragma unroll
    for (int j = 0; j < 4; ++j) {
#define XPV(g) bf2f((uint16_t)((j & 1) ? (xpf[g][j >> 1] >> 16) : (xpf[g][j >> 1] & 0xffff)))
      const float gi = __builtin_fmaf((float)acc[0][j], sc[0], XPV(0));
      const float gf = __builtin_fmaf((float)acc[1][j], sc[1], XPV(1));
      const float gg = __builtin_fmaf((float)acc[2][j], sc[2], XPV(2));
      const float go = __builtin_fmaf((float)acc[3][j], sc[3], XPV(3));
      const float gr = __builtin_fmaf((float)acc[4][j], sc[4], XPV(4));
#undef XPV
      const float cn = sigm2(gf) * c[j] + sigm2(gi) * tanh2(gg) + sigm2(gr) * mv[j];
      c[j] = cn;
      hnew[j] = sigm2(go) * tanh2(cn * L2E2);
    }

    // prefetch next step into the (now free) xpf/mv regs — overlaps barrier + next MFMA
    const uint16_t* xpb_n = xpb + 4 * NGT * 256;                 // beyond-chunk read stays in ws
    const float*    mb_n  = (s + 1 < s1) ? mb + BATCH * HID : mb;
#pragma unroll
    for (int g = 0; g < NGATE; ++g)
      xpf[g] = *reinterpret_cast<const u32x2*>(xpb_n + g * 4096);
#pragma unroll
    for (int j = 0; j < 4; ++j) mv[j] = mb_n[j * HID];
    xpb = xpb_n; mb = mb_n;

    // outputs + quantized h into next LDS buffer
#pragma unroll
    for (int j = 0; j < 4; ++j) {
      __builtin_nontemporal_store(hnew[j], sqb + j * HID);
      hw[woff[j]] = (int8_t)__float2int_rn(hnew[j] * 127.f);
    }
    if (s == T_LEN - 1) {
#pragma unroll
      for (int j = 0; j < 4; ++j) {
        hT[(size_t)(brow + bj0 + j) * HID + col] = hnew[j];
        cT[(size_t)(brow + bj0 + j) * HID + col] = c[j];
      }
    }
    sqb += BATCH * HID;

    // raw barrier: only LDS ordering needed (global loads/stores keep flying)
    __builtin_amdgcn_sched_barrier(0);
    asm volatile("s_waitcnt lgkmcnt(0)" ::: "memory");
    __builtin_amdgcn_s_barrier();
    __builtin_amdgcn_sched_barrier(0);
  }

  // persist c for next chunk
#pragma unroll
  for (int j = 0; j < 4; ++j)
    cbuf[(size_t)(brow + bj0 + j) * HID + col] = c[j];
}

extern "C" void kernel_launch(void* const* d_in, const int* in_sizes, int n_in,
                              void* d_out, int out_size, void* d_ws, size_t ws_size,
                              hipStream_t stream) {
  (void)in_sizes; (void)n_in; (void)out_size;
  const float* x    = (const float*)d_in[0];
  const float* mIn  = (const float*)d_in[1];
  const float* h0   = (const float*)d_in[2];
  const float* c0   = (const float*)d_in[3];
  const float* Wih  = (const float*)d_in[4];
  const float* Whh  = (const float*)d_in[5];
  const float* bias = (const float*)d_in[6];
  float* out = (float*)d_out;
  float* seq = out;
  float* hT  = out + (size_t)T_LEN * BATCH * HID;
  float* cT  = hT + (size_t)BATCH * HID;

  // ws: xp(bf16) + wihb(bf16) + wq(i8) + wsc(f32) + cbuf(f32)
  const size_t fixed = (size_t)GROWS * KDIM * 2 + (size_t)GROWS * KDIM
                     + (size_t)GROWS * 4 + (size_t)BATCH * HID * 4 + 4096;
  int tchunk = T_LEN;
  while (tchunk > 2 && (size_t)tchunk * BATCH * GROWS * 2 + fixed > ws_size) tchunk >>= 1;

  char* p = (char*)d_ws;
  uint16_t* xp   = (uint16_t*)p;  p += (size_t)tchunk * BATCH * GROWS * 2;
  uint16_t* wihb = (uint16_t*)p;  p += (size_t)GROWS * KDIM * 2;
  int8_t*   wq   = (int8_t*)p;    p += (size_t)GROWS * KDIM;
  float*    wsc  = (float*)p;     p += (size_t)GROWS * 4;
  float*    cbuf = (float*)p;

  setup_kernel<<<dim3((GROWS * KDIM + 255) / 256), dim3(256), 0, stream>>>(
      Wih, c0, wihb, cbuf);
  wquant_kernel<<<dim3((GROWS + 255) / 256), dim3(256), 0, stream>>>(Whh, wq, wsc);
  for (int s0 = 0; s0 < T_LEN; s0 += tchunk) {
    xproj_kernel<<<dim3(tchunk / 2), dim3(256), 0, stream>>>(x, wihb, bias, xp, s0);
    const float* h_src = (s0 == 0) ? h0 : (seq + (size_t)(s0 - 1) * BATCH * HID);
    scan_kernel<<<dim3(NSWG), dim3(1024), 0, stream>>>(
        mIn, wq, wsc, xp, h_src, cbuf, seq, hT, cT, s0, s0 + tchunk);
  }
}